// Round 13
// baseline (239.312 us; speedup 1.0000x reference)
//
#include <hip/hip_runtime.h>
#include <hip/hip_bf16.h>
#include <stdint.h>

// ---------------------------------------------------------------------------
// MaskedAttention: out = colsoftmax(tril(Q K^T / sqrt(E))) @ V
// B=4, T=2048, E=H=1024.  Softmax over the QUERY axis (axis=1) per column j.
//
// R23 (R22: gload_lds+linear-LDS PASSED (so it wasn't the R11-13 bug) but
// QKV 63->72.8us, bank-conflicts 0->1.9e7 -> reg-staging+swizzle wins on
// this skeleton.  Reverted):
//  * QKV: R17 register staging + swizzled LDS, BUT double-buffered (64KB,
//    2 bufs) with ONE barrier per K-step: iter reads buf[p] while storing
//    tile k+1 into buf[p^1] (disjoint); end-of-iter barrier orders reads
//    of p before next iter's writes of p.  Kills the 2-barrier drain stall.
//    Occupancy stays 2 blocks/CU (R17 measured ~25% = already 2).
//  * prep / scores64 / colsum_scale / pv128: R17-exact.
//
// Workspace 80 MB, liveness overlays:
//   [ 0,16) Xb      (dead after QKV)      -> Eb [0,32) at scores step
//   [16,22) WqT|WkT|WvT contiguous [3072,1024] (dead after QKV)
//   [32,48) Qb      (dead after scores)
//   [48,64) Kb      (dead after scores)
//   [64,80) Vt [B,H,T] (QKV epilogue, scaled in place, read by PV)
//   partial column sums [B,32,T] fp32 (1 MB) live in d_out (dead until PV).
// ---------------------------------------------------------------------------

typedef short bf16x8 __attribute__((ext_vector_type(8)));
typedef float f32x4  __attribute__((ext_vector_type(4)));

__device__ __forceinline__ unsigned short f2bf(float f) {
    union { float f; unsigned u; } x; x.f = f;
    unsigned r = x.u + 0x7FFFu + ((x.u >> 16) & 1u);
    return (unsigned short)(r >> 16);
}
__device__ __forceinline__ float bf2f(unsigned short h) {
    union { unsigned u; float f; } x; x.u = ((unsigned)h) << 16;
    return x.f;
}

// ---------------------------------------------------------------------------
// prep: blocks [0,8192) cast X fp32->bf16 (4 elems/thread);
//       blocks [8192,8960) transpose+cast Wq/Wk/Wv [1024,1024] -> WT.
// ---------------------------------------------------------------------------
__global__ __launch_bounds__(256) void prep_kernel(
    const float* __restrict__ X,
    const float* __restrict__ Wq, const float* __restrict__ Wk,
    const float* __restrict__ Wv,
    unsigned short* __restrict__ Xb, unsigned short* __restrict__ WT)
{
    __shared__ unsigned short tile[64][65];
    unsigned id = blockIdx.x;
    if (id < 8192) {
        size_t i = ((size_t)id * 256 + threadIdx.x) * 4;
        float4 v = *(const float4*)(X + i);
        union { unsigned short h[4]; unsigned long long u; } p;
        p.h[0] = f2bf(v.x); p.h[1] = f2bf(v.y);
        p.h[2] = f2bf(v.z); p.h[3] = f2bf(v.w);
        *(unsigned long long*)(Xb + i) = p.u;
    } else {
        unsigned w = id - 8192;
        unsigned which = w >> 8;                 // 0,1,2
        const float* W = (which == 0) ? Wq : (which == 1) ? Wk : Wv;
        unsigned short* out = WT + (size_t)which * 1024 * 1024;
        const int R = 1024, C = 1024;
        unsigned t2 = w & 255;
        int c0 = (int)(t2 & 15) * 64, r0 = (int)(t2 >> 4) * 64;
        int tx = threadIdx.x & 63, ty = threadIdx.x >> 6;
#pragma unroll
        for (int i = 0; i < 16; ++i) {
            int r = ty + i * 4;
            tile[r][tx] = f2bf(W[(size_t)(r0 + r) * C + c0 + tx]);
        }
        __syncthreads();
#pragma unroll
        for (int i = 0; i < 16; ++i) {
            int c = ty + i * 4;
            out[(size_t)(c0 + c) * R + r0 + tx] = tile[tx][c];
        }
    }
}

// ---------------------------------------------------------------------------
// Fused QKV (bf16): C[M,3H] = Xb[M,K] * WT[3H,K]^T.  128x128 tile, BK=64,
// 256 thr = 4 waves, XCD-banded (8 tm x 24 tn per XCD), 1536 blocks.
// Register staging + swizzled LDS (R17), double-buffered: ONE barrier per
// K-step (reads buf[p] || stores tile k+1 -> buf[p^1], disjoint).
// ---------------------------------------------------------------------------
__global__ __launch_bounds__(256, 3) void gemm_nt_qkv(
    const unsigned short* __restrict__ A, const unsigned short* __restrict__ B,
    unsigned short* __restrict__ Cout, unsigned short* __restrict__ C2,
    unsigned short* __restrict__ C3, int K, int ldt)
{
    unsigned id = blockIdx.y * gridDim.x + blockIdx.x;
    unsigned xcd = id & 7, k2 = id >> 3;
    int tm = (int)(xcd * 8 + (k2 & 7));
    int tn = (int)(k2 >> 3);
    int m0 = tm * 128, n0 = tn * 128;

    __shared__ unsigned short sAB[2][2 * 128 * 64];   // 2 x (A 16KB | B 16KB)

    unsigned t = threadIdx.x, lane = t & 63, wave = t >> 6;

    // staging: chunk ca = t + 256q, row = (ca&511)>>2, LDS byte ca*16.
    // Swizzle: global 16B group g = (ca&3) ^ ((row>>1)&3).
    unsigned srow = t >> 2;
    unsigned gsw = (t & 3) ^ ((t >> 3) & 3);
    const unsigned short* pA = A + (size_t)(m0 + srow) * K + gsw * 8;
    const unsigned short* pB = B + (size_t)(n0 + srow) * K + gsw * 8;
    const size_t rstep = (size_t)64 * K;
    unsigned ldsOff = t * 16;

    unsigned wm = (wave >> 1) * 64, wn = (wave & 1) * 64;
    unsigned lrow = lane & 15;
    unsigned lk = ((lane >> 4) ^ ((lane >> 1) & 3)) * 8;

    f32x4 acc[4][4] = {};

    // tile 0 -> regs -> buf0
    int4 rA0 = *(const int4*)(pA);
    int4 rA1 = *(const int4*)(pA + rstep);
    int4 rA2 = *(const int4*)(pA + 32);
    int4 rA3 = *(const int4*)(pA + rstep + 32);
    int4 rB0 = *(const int4*)(pB);
    int4 rB1 = *(const int4*)(pB + rstep);
    int4 rB2 = *(const int4*)(pB + 32);
    int4 rB3 = *(const int4*)(pB + rstep + 32);
    {
        char* sAc = (char*)sAB[0];
        char* sBc = (char*)sAB[0] + 16384;
        *(int4*)(sAc + ldsOff)         = rA0;
        *(int4*)(sAc + ldsOff + 4096)  = rA1;
        *(int4*)(sAc + ldsOff + 8192)  = rA2;
        *(int4*)(sAc + ldsOff + 12288) = rA3;
        *(int4*)(sBc + ldsOff)         = rB0;
        *(int4*)(sBc + ldsOff + 4096)  = rB1;
        *(int4*)(sBc + ldsOff + 8192)  = rB2;
        *(int4*)(sBc + ldsOff + 12288) = rB3;
    }
    __syncthreads();

    unsigned p = 0;
    for (int k0 = 0; k0 < K; k0 += 64, p ^= 1) {
        bool more = (k0 + 64 < K);
        if (more) {                      // issue next-tile loads; land during MFMA
            pA += 64; pB += 64;
            rA0 = *(const int4*)(pA);
            rA1 = *(const int4*)(pA + rstep);
            rA2 = *(const int4*)(pA + 32);
            rA3 = *(const int4*)(pA + rstep + 32);
            rB0 = *(const int4*)(pB);
            rB1 = *(const int4*)(pB + rstep);
            rB2 = *(const int4*)(pB + 32);
            rB3 = *(const int4*)(pB + rstep + 32);
        }

        const short* sAs = (const short*)sAB[p];
        const short* sBs = (const short*)(sAB[p] + 128 * 64);
#pragma unroll
        for (int kk = 0; kk < 2; ++kk) {
            bf16x8 a[4], b[4];
#pragma unroll
            for (int i = 0; i < 4; ++i) {
                a[i] = *(const bf16x8*)(sAs + kk * 4096 + (wm + i * 16 + lrow) * 32 + lk);
                b[i] = *(const bf16x8*)(sBs + kk * 4096 + (wn + i * 16 + lrow) * 32 + lk);
            }
#pragma unroll
            for (int i = 0; i < 4; ++i)
#pragma unroll
                for (int j = 0; j < 4; ++j)
                    acc[i][j] = __builtin_amdgcn_mfma_f32_16x16x32_bf16(
                        a[i], b[j], acc[i][j], 0, 0, 0);
        }

        if (more) {                      // store tile k+1 into the OTHER buffer
            char* sAc = (char*)sAB[p ^ 1];
            char* sBc = (char*)sAB[p ^ 1] + 16384;
            *(int4*)(sAc + ldsOff)         = rA0;
            *(int4*)(sAc + ldsOff + 4096)  = rA1;
            *(int4*)(sAc + ldsOff + 8192)  = rA2;
            *(int4*)(sAc + ldsOff + 12288) = rA3;
            *(int4*)(sBc + ldsOff)         = rB0;
            *(int4*)(sBc + ldsOff + 4096)  = rB1;
            *(int4*)(sBc + ldsOff + 8192)  = rB2;
            *(int4*)(sBc + ldsOff + 12288) = rB3;
        }
        __syncthreads();                 // reads of p done; writes of p^1 published
    }

    unsigned col = lane & 15, rq = (lane >> 4) * 4;
    if (n0 < 2048) {      // Q or K, row-major [8192,1024]
        unsigned short* C = (n0 < 1024) ? Cout : C2;
        int nb = n0 & 1023;
#pragma unroll
        for (int i = 0; i < 4; ++i)
#pragma unroll
            for (int j = 0; j < 4; ++j)
#pragma unroll
                for (int r = 0; r < 4; ++r)
                    C[(size_t)(m0 + wm + i * 16 + rq + r) * 1024 + nb + wn + j * 16 + col] =
                        f2bf(acc[i][j][r]);
    } else {              // V transposed into Vt [B,H,T]
        int batch = m0 >> 11, tb = m0 & 2047;
        unsigned short* C = C3 + (size_t)batch * 1024 * 2048;
#pragma unroll
        for (int i = 0; i < 4; ++i)
#pragma unroll
            for (int j = 0; j < 4; ++j) {
                union { unsigned short h[4]; unsigned long long u; } p2;
#pragma unroll
                for (int r = 0; r < 4; ++r) p2.h[r] = f2bf(acc[i][j][r]);
                int h = (n0 - 2048) + wn + j * 16 + col;
                int t0 = tb + wm + i * 16 + rq;
                *(unsigned long long*)(C + (size_t)h * ldt + t0) = p2.u;
            }
    }
}

// ---------------------------------------------------------------------------
// scores64: E = exp(scale * Q K^T) masked causal, 128x64 tiles, + column
// partials par[b][rh][j].  Grid (272,1,B): xcd-chunked triangular decode.
// 4 waves of 64x32 out; LDS 24KB -> 4 blocks/CU with launch_bounds(256,4).
// (R17-verified, byte-identical.)
// ---------------------------------------------------------------------------
__global__ __launch_bounds__(256, 4) void scores64_kernel(
    const unsigned short* __restrict__ A, const unsigned short* __restrict__ B,
    unsigned short* __restrict__ Eb, float* __restrict__ fpar, float scale)
{
    int bz = blockIdx.z;
    unsigned bx = blockIdx.x;                    // [0,272)
    int u = (int)((bx & 7u) * 34u + (bx >> 3));
    int tm = (int)((sqrtf(4.f * (float)u + 1.f) - 1.f) * 0.5f);
    while ((tm + 1) * (tm + 2) <= u) ++tm;
    while (tm * (tm + 1) > u) --tm;
    int tn64 = u - tm * (tm + 1);                // [0, 2tm+2)
    const int K = 1024;
    int m0 = tm * 128, n0 = tn64 * 64;
    A += (size_t)bz * (size_t)2048 * 1024;       // Qb batch panel
    B += (size_t)bz * (size_t)2048 * 1024;       // Kb batch panel

    __shared__ unsigned short sAB[12288];        // A 16KB + B 8KB
    char* sAc = (char*)sAB;
    char* sBc = (char*)sAB + 16384;

    unsigned t = threadIdx.x, lane = t & 63, wave = t >> 6;
    unsigned srow = t >> 2;                      // [0,64)
    unsigned gsw = (t & 3) ^ ((t >> 3) & 3);     // key = (row>>1)&3
    const unsigned short* pA = A + (size_t)(m0 + srow) * K + gsw * 8;
    const unsigned short* pB = B + (size_t)(n0 + srow) * K + gsw * 8;
    const size_t rstep = (size_t)64 * K;
    unsigned ldsOff = t * 16;

    unsigned wm = (wave >> 1) * 64, wn = (wave & 1) * 32;
    unsigned lrow = lane & 15;
    unsigned lk = ((lane >> 4) ^ ((lane >> 1) & 3)) * 8;
    const short* sAs = (const short*)sAB;
    const short* sBs = (const short*)(sAB + 8192);   // byte 16384

    f32x4 acc[4][2] = {};

    int4 rA0 = *(const int4*)(pA);
    int4 rA1 = *(const int4*)(pA + rstep);
    int4 rA2 = *(const int4*)(pA + 32);
    int4 rA3 = *(const int4*)(pA + rstep + 32);
    int4 rB0 = *(const int4*)(pB);
    int4 rB1 = *(const int4*)(pB + 32);

    for (int k0 = 0; k0 < K; k0 += 64) {
        __syncthreads();
        *(int4*)(sAc + ldsOff)         = rA0;
        *(int4*)(sAc + ldsOff + 4096)  = rA1;
        *(int4*)(sAc + ldsOff + 8192)  = rA2;
        *(int4*)(sAc + ldsOff + 12288) = rA3;
        *(int4*)(sBc + ldsOff)         = rB0;
        *(int4*)(sBc + ldsOff + 4096)  = rB1;
        __syncthreads();

        if (k0 + 64 < K) {
            pA += 64; pB += 64;
            rA0 = *(const int4*)(pA);
            rA1 = *(const int4*)(pA + rstep);
            rA2 = *(const int4*)(pA + 32);
            rA3 = *(const int4*)(pA + rstep + 32);
            rB0 = *(const int4*)(pB);
            rB1 = *(const int4*)(pB + 32);
        }

#pragma unroll
        for (int kk = 0; kk < 2; ++kk) {
            bf16x8 a[4], b[2];
#pragma unroll
            for (int i = 0; i < 4; ++i)
                a[i] = *(const bf16x8*)(sAs + kk * 4096 + (wm + i * 16 + lrow) * 32 + lk);
#pragma unroll
            for (int j = 0; j < 2; ++j)
                b[j] = *(const bf16x8*)(sBs + kk * 2048 + (wn + j * 16 + lrow) * 32 + lk);
#pragma unroll
            for (int i = 0; i < 4; ++i)
#pragma unroll
                for (int j = 0; j < 2; ++j)
                    acc[i][j] = __builtin_amdgcn_mfma_f32_16x16x32_bf16(
                        a[i], b[j], acc[i][j], 0, 0, 0);
        }
    }

    // epilogue: exp + mask -> LDS tile [128][64] + column partials
    unsigned col = lane & 15, rq = (lane >> 4) * 4;
    unsigned short* Ebp = Eb + (size_t)bz * (size_t)2048 * 2048;
    float* par = fpar + (size_t)bz * 32 * 2048;
    bool diag = ((tn64 >> 1) == tm);
    unsigned short* tile = sAB;                  // [128][64] bf16 = 16KB
    __syncthreads();                             // A/B LDS reads complete
#pragma unroll
    for (int jj = 0; jj < 2; ++jj) {
        float csum = 0.f;
        int jl = (int)(wn + jj * 16 + col);
        int jg = n0 + jl;
#pragma unroll
        for (int ii = 0; ii < 4; ++ii) {
#pragma unroll
            for (int r = 0; r < 4; ++r) {
                int il = (int)(wm + ii * 16 + rq + r);
                int ig = m0 + il;
                unsigned short us = 0;
                if (!diag || ig >= jg)
                    us = f2bf(__expf(acc[ii][jj][r] * scale));
                tile[il * 64 + jl] = us;
                csum += bf2f(us);
            }
        }
        csum += __shfl_xor(csum, 16);
        csum += __shfl_xor(csum, 32);
        if (lane < 16) {
            int rh = (m0 + (int)wm) >> 6;
            par[(size_t)rh * 2048 + n0 + wn + jj * 16 + lane] = csum;
        }
    }
    __syncthreads();
    // coalesced store: 4 passes x 256 threads x 16B
    {
        unsigned rr = t >> 3, cc = (t & 7) * 8;
#pragma unroll
        for (int p = 0; p < 4; ++p) {
            int li = (int)(p * 32 + rr);
            int4 v = *(const int4*)(tile + li * 64 + cc);
            *(int4*)(Ebp + (size_t)(m0 + li) * 2048 + n0 + cc) = v;
        }
    }
}

// ---------------------------------------------------------------------------
// pv128: out[i][h] = sum_j E[i][j] Vs[h][j]  (NT, A=E [T,T], B=scaled Vt
// [H,T], causal kmax = m0+128).  128x128 tiles, 512-block complement-paired
// 1D grid (R16/R17-verified mapping).
// ---------------------------------------------------------------------------
__global__ __launch_bounds__(256, 3) void pv128_kernel(
    const unsigned short* __restrict__ A, const unsigned short* __restrict__ B,
    float* __restrict__ out)
{
    unsigned n = blockIdx.x;           // [0,512)
    int tn = (int)(n & 7u);
    unsigned q = n >> 3, half = q >> 5, r = q & 31u;
    int bz = (int)((half ? 2u : 0u) + (r & 1u));
    int tm = half ? (int)(r >> 1) : (int)(15u - (r >> 1));
    const int K = 2048, N = 1024;
    int m0 = tm * 128, n0 = tn * 128;
    int kmax = m0 + 128;
    A += (size_t)bz * (size_t)2048 * 2048;       // E batch panel
    B += (size_t)bz * (size_t)1024 * 2048;       // Vt batch panel

    __shared__ unsigned short sAB[2 * 128 * 64];
    char* sAc = (char*)sAB;
    char* sBc = (char*)sAB + 16384;

    unsigned t = threadIdx.x, lane = t & 63, wave = t >> 6;

    unsigned srow = t >> 2;
    unsigned gsw = (t & 3) ^ ((t >> 3) & 3);
    const unsigned short* pA = A + (size_t)(m0 + srow) * K + gsw * 8;
    const unsigned short* pB = B + (size_t)(n0 + srow) * K + gsw * 8;
    const size_t rstep = (size_t)64 * K;
    unsigned ldsOff = t * 16;

    unsigned wm = (wave >> 1) * 64, wn = (wave & 1) * 64;
    unsigned lrow = lane & 15;
    unsigned lk = ((lane >> 4) ^ ((lane >> 1) & 3)) * 8;
    const short* sAs = (const short*)sAB;
    const short* sBs = (const short*)(sAB + 128 * 64);

    f32x4 acc[4][4] = {};

    int4 rA0 = *(const int4*)(pA);
    int4 rA1 = *(const int4*)(pA + rstep);
    int4 rA2 = *(const int4*)(pA + 32);
    int4 rA3 = *(const int4*)(pA + rstep + 32);
    int4 rB0 = *(const int4*)(pB);
    int4 rB1 = *(const int4*)(pB + rstep);
    int4 rB2 = *(const int4*)(pB + 32);
    int4 rB3 = *(const int4*)(pB + rstep + 32);

    for (int k0 = 0; k0 < kmax; k0 += 64) {
        __syncthreads();
        *(int4*)(sAc + ldsOff)         = rA0;
        *(int4*)(sAc + ldsOff + 4096)  = rA1;
        *(int4*)(sAc + ldsOff + 8192)  = rA2;
        *(int4*)(sAc + ldsOff + 12288) = rA3;
        *(int4*)(sBc + ldsOff)         = rB0;
        *(int4*)(sBc + ldsOff + 4096)  = rB1;
        *(int4*)(sBc + ldsOff + 8192)  = rB2;
        *(int4*)(sBc + ldsOff + 12288) = rB3;
        __syncthreads();

        if (k0 + 64 < kmax) {
            pA += 64; pB += 64;
            rA0 = *(const int4*)(pA);
            rA1 = *(const int4*)(pA + rstep);
            rA2 = *(const int4*)(pA + 32);
            rA3 = *(const int4*)(pA + rstep + 32);
            rB0 = *(const int4*)(pB);
            rB1 = *(const int4*)(pB + rstep);
            rB2 = *(const int4*)(pB + 32);
            rB3 = *(const int4*)(pB + rstep + 32);
        }

#pragma unroll
        for (int kk = 0; kk < 2; ++kk) {
            bf16x8 a[4], b[4];
#pragma unroll
            for (int i = 0; i < 4; ++i) {
                a[i] = *(const bf16x8*)(sAs + kk * 4096 + (wm + i * 16 + lrow) * 32 + lk);
                b[i] = *(const bf16x8*)(sBs + kk * 4096 + (wn + i * 16 + lrow) * 32 + lk);
            }
#pragma unroll
            for (int i = 0; i < 4; ++i)
#pragma unroll
                for (int j = 0; j < 4; ++j)
                    acc[i][j] = __builtin_amdgcn_mfma_f32_16x16x32_bf16(
                        a[i], b[j], acc[i][j], 0, 0, 0);
        }
    }

    unsigned col = lane & 15, rq = (lane >> 4) * 4;
    float* C = out + (size_t)bz * (size_t)2048 * 1024;
#pragma unroll
    for (int i = 0; i < 4; ++i)
#pragma unroll
        for (int j = 0; j < 4; ++j)
#pragma unroll
            for (int r = 0; r < 4; ++r)
                C[(size_t)(m0 + wm + i * 16 + rq + r) * N + n0 + wn + j * 16 + col] =
                    acc[i][j][r];
}

// ---------------------------------------------------------------------------
// colsum_scale: Linv[j] = 1/sum_rh par[b][rh][j] (rh >= j>>6), then
// Vt[b][h0..h0+128)[t0..t0+64) *= Linv.  Grid (32, 8, 4) = 1024 blocks.
// (R17-verified, byte-identical.)
// ---------------------------------------------------------------------------
__global__ __launch_bounds__(256) void colsum_scale(
    const float* __restrict__ par, unsigned short* __restrict__ Vt)
{
    int b = blockIdx.z, t0 = blockIdx.x * 64, h0 = blockIdx.y * 128;
    __shared__ float Ls[64];
    int tid = threadIdx.x;
    if (tid < 64) {
        int j = t0 + tid;
        const float* p = par + (size_t)b * 32 * 2048;
        float s = 0.f;
        for (int rh = j >> 6; rh < 32; ++rh) s += p[(size_t)rh * 2048 + j];
        Ls[tid] = 1.0f / s;
    }
    __syncthreads();
    unsigned short* V = Vt + ((size_t)b << 21);
    int c8 = (tid & 7) * 8;
#pragma unroll
    for (int rr = 0; rr < 4; ++rr) {
        int h = h0 + rr * 32 + (tid >> 3);
        size_t idx = (size_t)h * 2048 + t0 + c8;
        bf16x8 v = *(bf16x8*)(V + idx);
#pragma unroll
        for (int e = 0; e < 8; ++e)
            v[e] = (short)f2bf(bf2f((unsigned short)v[e]) * Ls[c8 + e]);
        *(bf16x8*)(V + idx) = v;
    }
}

// ---------------------------------------------------------------------------
extern "C" void kernel_launch(void* const* d_in, const int* in_sizes, int n_in,
                              void* d_out, int out_size, void* d_ws, size_t ws_size,
                              hipStream_t stream)
{
    const int B = 4, T = 2048, E = 1024, H = 1024;
    const int M = B * T;                       // 8192
    const float* X  = (const float*)d_in[0];
    const float* Wq = (const float*)d_in[1];
    const float* Wk = (const float*)d_in[2];
    const float* Wv = (const float*)d_in[3];
    float* out = (float*)d_out;
    char* ws = (char*)d_ws;
    const size_t MB = 1024 * 1024;

    unsigned short* Xb  = (unsigned short*)(ws + 0);        // [ 0,16) MB
    unsigned short* WqT = (unsigned short*)(ws + 16 * MB);  // [16,22) contiguous q|k|v
    unsigned short* Qb  = (unsigned short*)(ws + 32 * MB);  // [32,48)
    unsigned short* Kb  = (unsigned short*)(ws + 48 * MB);  // [48,64)
    unsigned short* Vt  = (unsigned short*)(ws + 64 * MB);  // [64,80) Vt [B,H,T]
    unsigned short* Eb  = (unsigned short*)(ws + 0);        // [ 0,32) overlays Xb/W (dead)
    float*          par  = (float*)d_out;                   // 1 MB, dead until PV

    // 1. fused prep: cast X (8192 blocks) + 3 weight transposes (768 blocks)
    prep_kernel<<<dim3(8960), 256, 0, stream>>>(X, Wq, Wk, Wv, Xb, WqT);

    // 2. fused QKV: [8192,3072] vs concat W^T; Q,K row-major, V -> Vt [B,H,T]
    gemm_nt_qkv<<<dim3(24, 64, 1), 256, 0, stream>>>(
        Xb, WqT, Qb, Kb, Vt, E, T);

    // 3. scores64: E[i][j] = exp((Q K^T)[i][j]/32) masked, + column partials
    scores64_kernel<<<dim3(272, 1, B), 256, 0, stream>>>(
        Qb, Kb, Eb, par, 0.03125f);

    // 4. Linv = 1/colsum fused with Vt *= Linv (1024 blocks)
    colsum_scale<<<dim3(32, 8, 4), 256, 0, stream>>>(par, Vt);

    // 5. pv128: out = E (V/L), causal K-limit, complement-paired 512 blocks
    pv128_kernel<<<dim3(512), 256, 0, stream>>>(Eb, Vt, out);
}

// Round 14
// 228.232 us; speedup vs baseline: 1.0485x; 1.0485x over previous
//
#include <hip/hip_runtime.h>
#include <hip/hip_bf16.h>
#include <stdint.h>

// ---------------------------------------------------------------------------
// MaskedAttention: out = colsoftmax(tril(Q K^T / sqrt(E))) @ V
// B=4, T=2048, E=H=1024.  Softmax over the QUERY axis (axis=1) per column j.
//
// R24 = R17-exact revert (session best, 224.4us verified).
// Experiment ledger on this base (all single-variable, all regressed):
//   R18 pv64 4/CU:        +9   (halved-N doubled E-panel fetch)
//   R19 QKV split:        +11  (1 dispatch boundary ~ 5-10us)
//   R20 fp32 A-staging:   +7   (FETCH 42->68MB; bf16 pre-cast is traffic opt)
//   R21 Linv in staging:  +10  (VALU between staging barriers)
//   R22 gload_lds+linear: +5   (1.9e7 bank conflicts > staging savings)
//   R23 LDS double-buf:   +15  (64KB LDS -> occupancy 12->8 waves/CU)
// Fill-poison memset (41us/iter, 82% HBM) is harness-fixed and inside the
// measured window.  Each kernel sits at its structure's measured optimum.
//
// Workspace 80 MB, liveness overlays:
//   [ 0,16) Xb      (dead after QKV)      -> Eb [0,32) at scores step
//   [16,22) WqT|WkT|WvT contiguous [3072,1024] (dead after QKV)
//   [32,48) Qb      (dead after scores)
//   [48,64) Kb      (dead after scores)
//   [64,80) Vt [B,H,T] (QKV epilogue, scaled in place, read by PV)
//   partial column sums [B,32,T] fp32 (1 MB) live in d_out (dead until PV).
// ---------------------------------------------------------------------------

typedef short bf16x8 __attribute__((ext_vector_type(8)));
typedef float f32x4  __attribute__((ext_vector_type(4)));

__device__ __forceinline__ unsigned short f2bf(float f) {
    union { float f; unsigned u; } x; x.f = f;
    unsigned r = x.u + 0x7FFFu + ((x.u >> 16) & 1u);
    return (unsigned short)(r >> 16);
}
__device__ __forceinline__ float bf2f(unsigned short h) {
    union { unsigned u; float f; } x; x.u = ((unsigned)h) << 16;
    return x.f;
}

// ---------------------------------------------------------------------------
// prep: blocks [0,8192) cast X fp32->bf16 (4 elems/thread);
//       blocks [8192,8960) transpose+cast Wq/Wk/Wv [1024,1024] -> WT.
// ---------------------------------------------------------------------------
__global__ __launch_bounds__(256) void prep_kernel(
    const float* __restrict__ X,
    const float* __restrict__ Wq, const float* __restrict__ Wk,
    const float* __restrict__ Wv,
    unsigned short* __restrict__ Xb, unsigned short* __restrict__ WT)
{
    __shared__ unsigned short tile[64][65];
    unsigned id = blockIdx.x;
    if (id < 8192) {
        size_t i = ((size_t)id * 256 + threadIdx.x) * 4;
        float4 v = *(const float4*)(X + i);
        union { unsigned short h[4]; unsigned long long u; } p;
        p.h[0] = f2bf(v.x); p.h[1] = f2bf(v.y);
        p.h[2] = f2bf(v.z); p.h[3] = f2bf(v.w);
        *(unsigned long long*)(Xb + i) = p.u;
    } else {
        unsigned w = id - 8192;
        unsigned which = w >> 8;                 // 0,1,2
        const float* W = (which == 0) ? Wq : (which == 1) ? Wk : Wv;
        unsigned short* out = WT + (size_t)which * 1024 * 1024;
        const int R = 1024, C = 1024;
        unsigned t2 = w & 255;
        int c0 = (int)(t2 & 15) * 64, r0 = (int)(t2 >> 4) * 64;
        int tx = threadIdx.x & 63, ty = threadIdx.x >> 6;
#pragma unroll
        for (int i = 0; i < 16; ++i) {
            int r = ty + i * 4;
            tile[r][tx] = f2bf(W[(size_t)(r0 + r) * C + c0 + tx]);
        }
        __syncthreads();
#pragma unroll
        for (int i = 0; i < 16; ++i) {
            int c = ty + i * 4;
            out[(size_t)(c0 + c) * R + r0 + tx] = tile[tx][c];
        }
    }
}

// ---------------------------------------------------------------------------
// Fused QKV (bf16): C[M,3H] = Xb[M,K] * WT[3H,K]^T.  128x128 tile, BK=64,
// 256 thr = 4 waves, XCD-banded (8 tm x 24 tn per XCD), 1536 blocks.
// Register staging + swizzled LDS, single-buffered 2-barrier (R17-exact).
// ---------------------------------------------------------------------------
__global__ __launch_bounds__(256, 3) void gemm_nt_qkv(
    const unsigned short* __restrict__ A, const unsigned short* __restrict__ B,
    unsigned short* __restrict__ Cout, unsigned short* __restrict__ C2,
    unsigned short* __restrict__ C3, int K, int ldt)
{
    unsigned id = blockIdx.y * gridDim.x + blockIdx.x;
    unsigned xcd = id & 7, k2 = id >> 3;
    int tm = (int)(xcd * 8 + (k2 & 7));
    int tn = (int)(k2 >> 3);
    int m0 = tm * 128, n0 = tn * 128;
    int kmax = K;

    __shared__ unsigned short sAB[2 * 128 * 64];
    char* sAc = (char*)sAB;
    char* sBc = (char*)sAB + 16384;

    unsigned t = threadIdx.x, lane = t & 63, wave = t >> 6;

    unsigned srow = t >> 2;
    unsigned gsw = (t & 3) ^ ((t >> 3) & 3);
    const unsigned short* pA = A + (size_t)(m0 + srow) * K + gsw * 8;
    const unsigned short* pB = B + (size_t)(n0 + srow) * K + gsw * 8;
    const size_t rstep = (size_t)64 * K;
    unsigned ldsOff = t * 16;

    unsigned wm = (wave >> 1) * 64, wn = (wave & 1) * 64;
    unsigned lrow = lane & 15;
    unsigned lk = ((lane >> 4) ^ ((lane >> 1) & 3)) * 8;
    const short* sAs = (const short*)sAB;
    const short* sBs = (const short*)(sAB + 128 * 64);

    f32x4 acc[4][4] = {};

    int4 rA0 = *(const int4*)(pA);
    int4 rA1 = *(const int4*)(pA + rstep);
    int4 rA2 = *(const int4*)(pA + 32);
    int4 rA3 = *(const int4*)(pA + rstep + 32);
    int4 rB0 = *(const int4*)(pB);
    int4 rB1 = *(const int4*)(pB + rstep);
    int4 rB2 = *(const int4*)(pB + 32);
    int4 rB3 = *(const int4*)(pB + rstep + 32);

    for (int k0 = 0; k0 < kmax; k0 += 64) {
        __syncthreads();
        *(int4*)(sAc + ldsOff)         = rA0;
        *(int4*)(sAc + ldsOff + 4096)  = rA1;
        *(int4*)(sAc + ldsOff + 8192)  = rA2;
        *(int4*)(sAc + ldsOff + 12288) = rA3;
        *(int4*)(sBc + ldsOff)         = rB0;
        *(int4*)(sBc + ldsOff + 4096)  = rB1;
        *(int4*)(sBc + ldsOff + 8192)  = rB2;
        *(int4*)(sBc + ldsOff + 12288) = rB3;
        __syncthreads();

        if (k0 + 64 < kmax) {
            pA += 64; pB += 64;
            rA0 = *(const int4*)(pA);
            rA1 = *(const int4*)(pA + rstep);
            rA2 = *(const int4*)(pA + 32);
            rA3 = *(const int4*)(pA + rstep + 32);
            rB0 = *(const int4*)(pB);
            rB1 = *(const int4*)(pB + rstep);
            rB2 = *(const int4*)(pB + 32);
            rB3 = *(const int4*)(pB + rstep + 32);
        }

#pragma unroll
        for (int kk = 0; kk < 2; ++kk) {
            bf16x8 a[4], b[4];
#pragma unroll
            for (int i = 0; i < 4; ++i) {
                a[i] = *(const bf16x8*)(sAs + kk * 4096 + (wm + i * 16 + lrow) * 32 + lk);
                b[i] = *(const bf16x8*)(sBs + kk * 4096 + (wn + i * 16 + lrow) * 32 + lk);
            }
#pragma unroll
            for (int i = 0; i < 4; ++i)
#pragma unroll
                for (int j = 0; j < 4; ++j)
                    acc[i][j] = __builtin_amdgcn_mfma_f32_16x16x32_bf16(
                        a[i], b[j], acc[i][j], 0, 0, 0);
        }
    }

    unsigned col = lane & 15, rq = (lane >> 4) * 4;
    if (n0 < 2048) {      // Q or K, row-major [8192,1024]
        unsigned short* C = (n0 < 1024) ? Cout : C2;
        int nb = n0 & 1023;
#pragma unroll
        for (int i = 0; i < 4; ++i)
#pragma unroll
            for (int j = 0; j < 4; ++j)
#pragma unroll
                for (int r = 0; r < 4; ++r)
                    C[(size_t)(m0 + wm + i * 16 + rq + r) * 1024 + nb + wn + j * 16 + col] =
                        f2bf(acc[i][j][r]);
    } else {              // V transposed into Vt [B,H,T]
        int batch = m0 >> 11, tb = m0 & 2047;
        unsigned short* C = C3 + (size_t)batch * 1024 * 2048;
#pragma unroll
        for (int i = 0; i < 4; ++i)
#pragma unroll
            for (int j = 0; j < 4; ++j) {
                union { unsigned short h[4]; unsigned long long u; } p;
#pragma unroll
                for (int r = 0; r < 4; ++r) p.h[r] = f2bf(acc[i][j][r]);
                int h = (n0 - 2048) + wn + j * 16 + col;
                int t0 = tb + wm + i * 16 + rq;
                *(unsigned long long*)(C + (size_t)h * ldt + t0) = p.u;
            }
    }
}

// ---------------------------------------------------------------------------
// scores64: E = exp(scale * Q K^T) masked causal, 128x64 tiles, + column
// partials par[b][rh][j].  Grid (272,1,B): xcd-chunked triangular decode.
// 4 waves of 64x32 out; LDS 24KB -> 4 blocks/CU with launch_bounds(256,4).
// ---------------------------------------------------------------------------
__global__ __launch_bounds__(256, 4) void scores64_kernel(
    const unsigned short* __restrict__ A, const unsigned short* __restrict__ B,
    unsigned short* __restrict__ Eb, float* __restrict__ fpar, float scale)
{
    int bz = blockIdx.z;
    unsigned bx = blockIdx.x;                    // [0,272)
    int u = (int)((bx & 7u) * 34u + (bx >> 3));
    int tm = (int)((sqrtf(4.f * (float)u + 1.f) - 1.f) * 0.5f);
    while ((tm + 1) * (tm + 2) <= u) ++tm;
    while (tm * (tm + 1) > u) --tm;
    int tn64 = u - tm * (tm + 1);                // [0, 2tm+2)
    const int K = 1024;
    int m0 = tm * 128, n0 = tn64 * 64;
    A += (size_t)bz * (size_t)2048 * 1024;       // Qb batch panel
    B += (size_t)bz * (size_t)2048 * 1024;       // Kb batch panel

    __shared__ unsigned short sAB[12288];        // A 16KB + B 8KB
    char* sAc = (char*)sAB;
    char* sBc = (char*)sAB + 16384;

    unsigned t = threadIdx.x, lane = t & 63, wave = t >> 6;
    unsigned srow = t >> 2;                      // [0,64)
    unsigned gsw = (t & 3) ^ ((t >> 3) & 3);     // key = (row>>1)&3
    const unsigned short* pA = A + (size_t)(m0 + srow) * K + gsw * 8;
    const unsigned short* pB = B + (size_t)(n0 + srow) * K + gsw * 8;
    const size_t rstep = (size_t)64 * K;
    unsigned ldsOff = t * 16;

    unsigned wm = (wave >> 1) * 64, wn = (wave & 1) * 32;
    unsigned lrow = lane & 15;
    unsigned lk = ((lane >> 4) ^ ((lane >> 1) & 3)) * 8;
    const short* sAs = (const short*)sAB;
    const short* sBs = (const short*)(sAB + 8192);   // byte 16384

    f32x4 acc[4][2] = {};

    int4 rA0 = *(const int4*)(pA);
    int4 rA1 = *(const int4*)(pA + rstep);
    int4 rA2 = *(const int4*)(pA + 32);
    int4 rA3 = *(const int4*)(pA + rstep + 32);
    int4 rB0 = *(const int4*)(pB);
    int4 rB1 = *(const int4*)(pB + 32);

    for (int k0 = 0; k0 < K; k0 += 64) {
        __syncthreads();
        *(int4*)(sAc + ldsOff)         = rA0;
        *(int4*)(sAc + ldsOff + 4096)  = rA1;
        *(int4*)(sAc + ldsOff + 8192)  = rA2;
        *(int4*)(sAc + ldsOff + 12288) = rA3;
        *(int4*)(sBc + ldsOff)         = rB0;
        *(int4*)(sBc + ldsOff + 4096)  = rB1;
        __syncthreads();

        if (k0 + 64 < K) {
            pA += 64; pB += 64;
            rA0 = *(const int4*)(pA);
            rA1 = *(const int4*)(pA + rstep);
            rA2 = *(const int4*)(pA + 32);
            rA3 = *(const int4*)(pA + rstep + 32);
            rB0 = *(const int4*)(pB);
            rB1 = *(const int4*)(pB + 32);
        }

#pragma unroll
        for (int kk = 0; kk < 2; ++kk) {
            bf16x8 a[4], b[2];
#pragma unroll
            for (int i = 0; i < 4; ++i)
                a[i] = *(const bf16x8*)(sAs + kk * 4096 + (wm + i * 16 + lrow) * 32 + lk);
#pragma unroll
            for (int j = 0; j < 2; ++j)
                b[j] = *(const bf16x8*)(sBs + kk * 2048 + (wn + j * 16 + lrow) * 32 + lk);
#pragma unroll
            for (int i = 0; i < 4; ++i)
#pragma unroll
                for (int j = 0; j < 2; ++j)
                    acc[i][j] = __builtin_amdgcn_mfma_f32_16x16x32_bf16(
                        a[i], b[j], acc[i][j], 0, 0, 0);
        }
    }

    // epilogue: exp + mask -> LDS tile [128][64] + column partials
    unsigned col = lane & 15, rq = (lane >> 4) * 4;
    unsigned short* Ebp = Eb + (size_t)bz * (size_t)2048 * 2048;
    float* par = fpar + (size_t)bz * 32 * 2048;
    bool diag = ((tn64 >> 1) == tm);
    unsigned short* tile = sAB;                  // [128][64] bf16 = 16KB
    __syncthreads();                             // A/B LDS reads complete
#pragma unroll
    for (int jj = 0; jj < 2; ++jj) {
        float csum = 0.f;
        int jl = (int)(wn + jj * 16 + col);
        int jg = n0 + jl;
#pragma unroll
        for (int ii = 0; ii < 4; ++ii) {
#pragma unroll
            for (int r = 0; r < 4; ++r) {
                int il = (int)(wm + ii * 16 + rq + r);
                int ig = m0 + il;
                unsigned short us = 0;
                if (!diag || ig >= jg)
                    us = f2bf(__expf(acc[ii][jj][r] * scale));
                tile[il * 64 + jl] = us;
                csum += bf2f(us);
            }
        }
        csum += __shfl_xor(csum, 16);
        csum += __shfl_xor(csum, 32);
        if (lane < 16) {
            int rh = (m0 + (int)wm) >> 6;
            par[(size_t)rh * 2048 + n0 + wn + jj * 16 + lane] = csum;
        }
    }
    __syncthreads();
    // coalesced store: 4 passes x 256 threads x 16B
    {
        unsigned rr = t >> 3, cc = (t & 7) * 8;
#pragma unroll
        for (int p = 0; p < 4; ++p) {
            int li = (int)(p * 32 + rr);
            int4 v = *(const int4*)(tile + li * 64 + cc);
            *(int4*)(Ebp + (size_t)(m0 + li) * 2048 + n0 + cc) = v;
        }
    }
}

// ---------------------------------------------------------------------------
// pv128: out[i][h] = sum_j E[i][j] Vs[h][j]  (NT, A=E [T,T], B=scaled Vt
// [H,T], causal kmax = m0+128).  128x128 tiles, 512-block complement-paired
// 1D grid (R16/R17-verified mapping).
// ---------------------------------------------------------------------------
__global__ __launch_bounds__(256, 3) void pv128_kernel(
    const unsigned short* __restrict__ A, const unsigned short* __restrict__ B,
    float* __restrict__ out)
{
    unsigned n = blockIdx.x;           // [0,512)
    int tn = (int)(n & 7u);
    unsigned q = n >> 3, half = q >> 5, r = q & 31u;
    int bz = (int)((half ? 2u : 0u) + (r & 1u));
    int tm = half ? (int)(r >> 1) : (int)(15u - (r >> 1));
    const int K = 2048, N = 1024;
    int m0 = tm * 128, n0 = tn * 128;
    int kmax = m0 + 128;
    A += (size_t)bz * (size_t)2048 * 2048;       // E batch panel
    B += (size_t)bz * (size_t)1024 * 2048;       // Vt batch panel

    __shared__ unsigned short sAB[2 * 128 * 64];
    char* sAc = (char*)sAB;
    char* sBc = (char*)sAB + 16384;

    unsigned t = threadIdx.x, lane = t & 63, wave = t >> 6;

    unsigned srow = t >> 2;
    unsigned gsw = (t & 3) ^ ((t >> 3) & 3);
    const unsigned short* pA = A + (size_t)(m0 + srow) * K + gsw * 8;
    const unsigned short* pB = B + (size_t)(n0 + srow) * K + gsw * 8;
    const size_t rstep = (size_t)64 * K;
    unsigned ldsOff = t * 16;

    unsigned wm = (wave >> 1) * 64, wn = (wave & 1) * 64;
    unsigned lrow = lane & 15;
    unsigned lk = ((lane >> 4) ^ ((lane >> 1) & 3)) * 8;
    const short* sAs = (const short*)sAB;
    const short* sBs = (const short*)(sAB + 128 * 64);

    f32x4 acc[4][4] = {};

    int4 rA0 = *(const int4*)(pA);
    int4 rA1 = *(const int4*)(pA + rstep);
    int4 rA2 = *(const int4*)(pA + 32);
    int4 rA3 = *(const int4*)(pA + rstep + 32);
    int4 rB0 = *(const int4*)(pB);
    int4 rB1 = *(const int4*)(pB + rstep);
    int4 rB2 = *(const int4*)(pB + 32);
    int4 rB3 = *(const int4*)(pB + rstep + 32);

    for (int k0 = 0; k0 < kmax; k0 += 64) {
        __syncthreads();
        *(int4*)(sAc + ldsOff)         = rA0;
        *(int4*)(sAc + ldsOff + 4096)  = rA1;
        *(int4*)(sAc + ldsOff + 8192)  = rA2;
        *(int4*)(sAc + ldsOff + 12288) = rA3;
        *(int4*)(sBc + ldsOff)         = rB0;
        *(int4*)(sBc + ldsOff + 4096)  = rB1;
        *(int4*)(sBc + ldsOff + 8192)  = rB2;
        *(int4*)(sBc + ldsOff + 12288) = rB3;
        __syncthreads();

        if (k0 + 64 < kmax) {
            pA += 64; pB += 64;
            rA0 = *(const int4*)(pA);
            rA1 = *(const int4*)(pA + rstep);
            rA2 = *(const int4*)(pA + 32);
            rA3 = *(const int4*)(pA + rstep + 32);
            rB0 = *(const int4*)(pB);
            rB1 = *(const int4*)(pB + rstep);
            rB2 = *(const int4*)(pB + 32);
            rB3 = *(const int4*)(pB + rstep + 32);
        }

#pragma unroll
        for (int kk = 0; kk < 2; ++kk) {
            bf16x8 a[4], b[4];
#pragma unroll
            for (int i = 0; i < 4; ++i) {
                a[i] = *(const bf16x8*)(sAs + kk * 4096 + (wm + i * 16 + lrow) * 32 + lk);
                b[i] = *(const bf16x8*)(sBs + kk * 4096 + (wn + i * 16 + lrow) * 32 + lk);
            }
#pragma unroll
            for (int i = 0; i < 4; ++i)
#pragma unroll
                for (int j = 0; j < 4; ++j)
                    acc[i][j] = __builtin_amdgcn_mfma_f32_16x16x32_bf16(
                        a[i], b[j], acc[i][j], 0, 0, 0);
        }
    }

    unsigned col = lane & 15, rq = (lane >> 4) * 4;
    float* C = out + (size_t)bz * (size_t)2048 * 1024;
#pragma unroll
    for (int i = 0; i < 4; ++i)
#pragma unroll
        for (int j = 0; j < 4; ++j)
#pragma unroll
            for (int r = 0; r < 4; ++r)
                C[(size_t)(m0 + wm + i * 16 + rq + r) * N + n0 + wn + j * 16 + col] =
                    acc[i][j][r];
}

// ---------------------------------------------------------------------------
// colsum_scale: Linv[j] = 1/sum_rh par[b][rh][j] (rh >= j>>6), then
// Vt[b][h0..h0+128)[t0..t0+64) *= Linv.  Grid (32, 8, 4) = 1024 blocks.
// ---------------------------------------------------------------------------
__global__ __launch_bounds__(256) void colsum_scale(
    const float* __restrict__ par, unsigned short* __restrict__ Vt)
{
    int b = blockIdx.z, t0 = blockIdx.x * 64, h0 = blockIdx.y * 128;
    __shared__ float Ls[64];
    int tid = threadIdx.x;
    if (tid < 64) {
        int j = t0 + tid;
        const float* p = par + (size_t)b * 32 * 2048;
        float s = 0.f;
        for (int rh = j >> 6; rh < 32; ++rh) s += p[(size_t)rh * 2048 + j];
        Ls[tid] = 1.0f / s;
    }
    __syncthreads();
    unsigned short* V = Vt + ((size_t)b << 21);
    int c8 = (tid & 7) * 8;
#pragma unroll
    for (int rr = 0; rr < 4; ++rr) {
        int h = h0 + rr * 32 + (tid >> 3);
        size_t idx = (size_t)h * 2048 + t0 + c8;
        bf16x8 v = *(bf16x8*)(V + idx);
#pragma unroll
        for (int e = 0; e < 8; ++e)
            v[e] = (short)f2bf(bf2f((unsigned short)v[e]) * Ls[c8 + e]);
        *(bf16x8*)(V + idx) = v;
    }
}

// ---------------------------------------------------------------------------
extern "C" void kernel_launch(void* const* d_in, const int* in_sizes, int n_in,
                              void* d_out, int out_size, void* d_ws, size_t ws_size,
                              hipStream_t stream)
{
    const int B = 4, T = 2048, E = 1024, H = 1024;
    const int M = B * T;                       // 8192
    const float* X  = (const float*)d_in[0];
    const float* Wq = (const float*)d_in[1];
    const float* Wk = (const float*)d_in[2];
    const float* Wv = (const float*)d_in[3];
    float* out = (float*)d_out;
    char* ws = (char*)d_ws;
    const size_t MB = 1024 * 1024;

    unsigned short* Xb  = (unsigned short*)(ws + 0);        // [ 0,16) MB
    unsigned short* WqT = (unsigned short*)(ws + 16 * MB);  // [16,22) contiguous q|k|v
    unsigned short* Qb  = (unsigned short*)(ws + 32 * MB);  // [32,48)
    unsigned short* Kb  = (unsigned short*)(ws + 48 * MB);  // [48,64)
    unsigned short* Vt  = (unsigned short*)(ws + 64 * MB);  // [64,80) Vt [B,H,T]
    unsigned short* Eb  = (unsigned short*)(ws + 0);        // [ 0,32) overlays Xb/W (dead)
    float*          par  = (float*)d_out;                   // 1 MB, dead until PV

    // 1. fused prep: cast X (8192 blocks) + 3 weight transposes (768 blocks)
    prep_kernel<<<dim3(8960), 256, 0, stream>>>(X, Wq, Wk, Wv, Xb, WqT);

    // 2. fused QKV: [8192,3072] vs concat W^T; Q,K row-major, V -> Vt [B,H,T]
    gemm_nt_qkv<<<dim3(24, 64, 1), 256, 0, stream>>>(
        Xb, WqT, Qb, Kb, Vt, E, T);

    // 3. scores64: E[i][j] = exp((Q K^T)[i][j]/32) masked, + column partials
    scores64_kernel<<<dim3(272, 1, B), 256, 0, stream>>>(
        Qb, Kb, Eb, par, 0.03125f);

    // 4. Linv = 1/colsum fused with Vt *= Linv (1024 blocks)
    colsum_scale<<<dim3(32, 8, 4), 256, 0, stream>>>(par, Vt);

    // 5. pv128: out = E (V/L), causal K-limit, complement-paired 512 blocks
    pv128_kernel<<<dim3(512), 256, 0, stream>>>(Eb, Vt, out);
}